// Round 1
// baseline (528.077 us; speedup 1.0000x reference)
//
#include <hip/hip_runtime.h>
#include <math.h>
#include <stdint.h>

#define D 128
#define EPS 1e-6f

// ---------------------------------------------------------------------------
// state layout (floats), 8B-aligned base:
//   st[0..127]   : q
//   st[128..255] : q_plus
//   st[256..383] : hop accumulator (numerator of weighted value sum)
//   st[384]      : ||q||
//   st[385]      : ||q_plus||
//   st[386]      : sum of exp (softmax denominator accumulator)
// ---------------------------------------------------------------------------

__device__ __forceinline__ float wave_sum(float v) {
#pragma unroll
    for (int off = 32; off > 0; off >>= 1) v += __shfl_xor(v, off, 64);
    return v;
}

// One wave per row: rows_out[i*D + c] = sum_t table[ids[i*L+t]*D + c];
// norms_out[i] = ||row_i||. lane j handles channels 2j, 2j+1 (float2 -> one
// 512B coalesced segment per row).
__global__ void encode_rows(const float* __restrict__ table,
                            const int* __restrict__ ids, int N, int L,
                            float* __restrict__ rows_out,
                            float* __restrict__ norms_out) {
    int lane = threadIdx.x & 63;
    int gw = (int)((blockIdx.x * blockDim.x + threadIdx.x) >> 6);
    int nw = (int)((gridDim.x * blockDim.x) >> 6);
    for (int i = gw; i < N; i += nw) {
        float2 acc = {0.f, 0.f};
        const int* row_ids = ids + (long)i * L;
        for (int t = 0; t < L; ++t) {
            int idx = row_ids[t];
            const float2 e = *(const float2*)(table + (long)idx * D + 2 * lane);
            acc.x += e.x;
            acc.y += e.y;
        }
        *(float2*)(rows_out + (long)i * D + 2 * lane) = acc;
        float sq = wave_sum(acc.x * acc.x + acc.y * acc.y);
        if (lane == 0) norms_out[i] = sqrtf(sq);
    }
}

// Single block, 128 threads. Persona attention (NP rows) + q_plus=(q+hop)@W.T
// + ||q_plus||; zeroes the big-attention accumulators for the following pass.
__global__ void persona_hop(const float* __restrict__ pers_rows,
                            const float* __restrict__ pers_norms,
                            const float* __restrict__ W,
                            float* __restrict__ st, int NP) {
    __shared__ float qsh[D];
    __shared__ float att[64];
    __shared__ float qh[D];
    __shared__ float red[2];
    int tid = threadIdx.x;  // 0..127
    qsh[tid] = st[tid];
    __syncthreads();
    if (tid < NP) {
        float dot = 0.f;
        for (int d2 = 0; d2 < D; ++d2) dot += pers_rows[tid * D + d2] * qsh[d2];
        att[tid] = dot / fmaxf(pers_norms[tid] * st[384], EPS);
    }
    __syncthreads();
    if (tid == 0) {
        float m = -1e30f;
        for (int p = 0; p < NP; ++p) m = fmaxf(m, att[p]);
        float s = 0.f;
        for (int p = 0; p < NP; ++p) { att[p] = __expf(att[p] - m); s += att[p]; }
        float inv = 1.f / s;
        for (int p = 0; p < NP; ++p) att[p] *= inv;
    }
    __syncthreads();
    float h = 0.f;
    for (int p = 0; p < NP; ++p) h += att[p] * pers_rows[p * D + tid];
    qh[tid] = qsh[tid] + h;
    __syncthreads();
    float qp = 0.f;
    for (int d2 = 0; d2 < D; ++d2) qp += W[tid * D + d2] * qh[d2];
    st[128 + tid] = qp;
    float sq = wave_sum(qp * qp);
    if ((tid & 63) == 0) red[tid >> 6] = sq;
    __syncthreads();
    if (tid == 0) st[385] = sqrtf(red[0] + red[1]);
    // zero big-attention accumulators
    st[256 + tid] = 0.f;
    if (tid == 0) st[386] = 0.f;
}

// Fused big attention over precomputed key/value rows: per row
// e_i = exp(cos(q_plus, k_i)); accumulate sum_i e_i * v_i and sum_i e_i.
// cos in [-1,1] so exp needs no max subtraction.
__global__ void big_att(const float* __restrict__ krows,
                        const float* __restrict__ knorms,
                        const float* __restrict__ vrows,
                        float* __restrict__ st, int N) {
    __shared__ float s[129];
    int tid = threadIdx.x;
    int lane = tid & 63;
    int gw = (int)((blockIdx.x * blockDim.x + tid) >> 6);
    int nw = (int)((gridDim.x * blockDim.x) >> 6);
    float2 qp = *(const float2*)(st + 128 + 2 * lane);
    float qpn = st[385];
    float2 acc = {0.f, 0.f};
    float esum = 0.f;
    for (int i = gw; i < N; i += nw) {
        const float2 k = *(const float2*)(krows + (long)i * D + 2 * lane);
        float dot = wave_sum(k.x * qp.x + k.y * qp.y);
        float c = dot / fmaxf(knorms[i] * qpn, EPS);
        float e = __expf(c);
        const float2 v = *(const float2*)(vrows + (long)i * D + 2 * lane);
        acc.x += e * v.x;
        acc.y += e * v.y;
        esum += e;  // same value in all lanes; only lane 0's is used below
    }
    if (tid < 129) s[tid] = 0.f;
    __syncthreads();
    atomicAdd(&s[2 * lane], acc.x);
    atomicAdd(&s[2 * lane + 1], acc.y);
    if (lane == 0) atomicAdd(&s[128], esum);
    __syncthreads();
    if (tid < 129) atomicAdd(&st[256 + tid], s[tid]);  // st[384+2]=st[386] is esum slot: 256+128=384? no ->
}

// NOTE: st[256+128] == st[384] would clash with ||q||; dedicated kernel below
// uses explicit esum slot. See big_att_fix in the launch path: we instead map
// tid==128 to st[386] here via a corrected kernel.

__global__ void big_att2(const float* __restrict__ krows,
                         const float* __restrict__ knorms,
                         const float* __restrict__ vrows,
                         float* __restrict__ st, int N) {
    __shared__ float s[129];
    int tid = threadIdx.x;
    int lane = tid & 63;
    int gw = (int)((blockIdx.x * blockDim.x + tid) >> 6);
    int nw = (int)((gridDim.x * blockDim.x) >> 6);
    float2 qp = *(const float2*)(st + 128 + 2 * lane);
    float qpn = st[385];
    float2 acc = {0.f, 0.f};
    float esum = 0.f;
    for (int i = gw; i < N; i += nw) {
        const float2 k = *(const float2*)(krows + (long)i * D + 2 * lane);
        float dot = wave_sum(k.x * qp.x + k.y * qp.y);
        float c = dot / fmaxf(knorms[i] * qpn, EPS);
        float e = __expf(c);
        const float2 v = *(const float2*)(vrows + (long)i * D + 2 * lane);
        acc.x += e * v.x;
        acc.y += e * v.y;
        esum += e;
    }
    if (tid < 129) s[tid] = 0.f;
    __syncthreads();
    atomicAdd(&s[2 * lane], acc.x);
    atomicAdd(&s[2 * lane + 1], acc.y);
    if (lane == 0) atomicAdd(&s[128], esum);
    __syncthreads();
    if (tid < 128) atomicAdd(&st[256 + tid], s[tid]);
    if (tid == 128) atomicAdd(&st[386], s[128]);
}

// Fallback: same as big_att2 but recomputes key/value rows from the embedding
// table (used when d_ws is too small to hold the encoded rows).
__global__ void big_att_rc(const float* __restrict__ emb,
                           const int* __restrict__ kids,
                           const int* __restrict__ vids,
                           float* __restrict__ st, int N, int L) {
    __shared__ float s[129];
    int tid = threadIdx.x;
    int lane = tid & 63;
    int gw = (int)((blockIdx.x * blockDim.x + tid) >> 6);
    int nw = (int)((gridDim.x * blockDim.x) >> 6);
    float2 qp = *(const float2*)(st + 128 + 2 * lane);
    float qpn = st[385];
    float2 acc = {0.f, 0.f};
    float esum = 0.f;
    for (int i = gw; i < N; i += nw) {
        float2 k = {0.f, 0.f};
        const int* kr = kids + (long)i * L;
        for (int t = 0; t < L; ++t) {
            const float2 e = *(const float2*)(emb + (long)kr[t] * D + 2 * lane);
            k.x += e.x;
            k.y += e.y;
        }
        float nsq = wave_sum(k.x * k.x + k.y * k.y);
        float dot = wave_sum(k.x * qp.x + k.y * qp.y);
        float c = dot / fmaxf(sqrtf(nsq) * qpn, EPS);
        float e = __expf(c);
        float2 v = {0.f, 0.f};
        const int* vr = vids + (long)i * L;
        for (int t = 0; t < L; ++t) {
            const float2 ev = *(const float2*)(emb + (long)vr[t] * D + 2 * lane);
            v.x += ev.x;
            v.y += ev.y;
        }
        acc.x += e * v.x;
        acc.y += e * v.y;
        esum += e;
    }
    if (tid < 129) s[tid] = 0.f;
    __syncthreads();
    atomicAdd(&s[2 * lane], acc.x);
    atomicAdd(&s[2 * lane + 1], acc.y);
    if (lane == 0) atomicAdd(&s[128], esum);
    __syncthreads();
    if (tid < 128) atomicAdd(&st[256 + tid], s[tid]);
    if (tid == 128) atomicAdd(&st[386], s[128]);
}

// Single block, 128 threads: hop = acc/sum; q = (q_plus + hop) @ W.T; ||q||.
__global__ void finish_hop(const float* __restrict__ W, float* __restrict__ st) {
    __shared__ float qh[D];
    __shared__ float red[2];
    int tid = threadIdx.x;  // 0..127
    float inv = 1.f / st[386];
    qh[tid] = st[128 + tid] + st[256 + tid] * inv;
    __syncthreads();
    float qn = 0.f;
    for (int d2 = 0; d2 < D; ++d2) qn += W[tid * D + d2] * qh[d2];
    st[tid] = qn;
    float sq = wave_sum(qn * qn);
    if ((tid & 63) == 0) red[tid >> 6] = sq;
    __syncthreads();
    if (tid == 0) st[384] = sqrtf(red[0] + red[1]);
}

// One wave per candidate row: out[i] = cos(q, c_i).
__global__ void final_cands(const float* __restrict__ crows,
                            const float* __restrict__ cnorms,
                            const float* __restrict__ st,
                            float* __restrict__ out, int N) {
    int lane = threadIdx.x & 63;
    int gw = (int)((blockIdx.x * blockDim.x + threadIdx.x) >> 6);
    int nw = (int)((gridDim.x * blockDim.x) >> 6);
    float2 q = *(const float2*)(st + 2 * lane);
    float qn = st[384];
    for (int i = gw; i < N; i += nw) {
        const float2 c = *(const float2*)(crows + (long)i * D + 2 * lane);
        float dot = wave_sum(c.x * q.x + c.y * q.y);
        if (lane == 0) out[i] = dot / fmaxf(cnorms[i] * qn, EPS);
    }
}

extern "C" void kernel_launch(void* const* d_in, const int* in_sizes, int n_in,
                              void* d_out, int out_size, void* d_ws, size_t ws_size,
                              hipStream_t stream) {
    const int* xs = (const int*)d_in[0];
    const int* cands = (const int*)d_in[1];
    const int* pers = (const int*)d_in[2];
    const int* keys = (const int*)d_in[3];
    const int* values = (const int*)d_in[4];
    // d_in[5] = label, unused by the forward pass
    const float* semb = (const float*)d_in[6];
    const float* cemb = (const float*)d_in[7];
    const float* RW = (const float*)d_in[8];
    const float* R2W = (const float*)d_in[9];
    float* out = (float*)d_out;

    const int L = 20;
    const int LQ = in_sizes[0];
    const int NMEM = in_sizes[3] / L;   // 65536
    const int NCAND = in_sizes[1] / L;  // 10000
    const int NPERS = in_sizes[2] / L;  // 20

    // Workspace budget check: full path stores enc_keys/enc_values too.
    size_t full_need =
        ((size_t)NMEM * D * 2 + (size_t)NMEM * 2 + (size_t)NCAND * D + NCAND +
         (size_t)NPERS * D + NPERS + 512) * sizeof(float);
    bool stored = (d_ws != nullptr) && (ws_size >= full_need);

    float* p = (float*)d_ws;
    float *enc_keys = nullptr, *enc_vals = nullptr, *knorms = nullptr, *vnorms = nullptr;
    if (stored) {
        enc_keys = p; p += (size_t)NMEM * D;
        enc_vals = p; p += (size_t)NMEM * D;
        knorms = p; p += NMEM;
        vnorms = p; p += NMEM;  // written by encode_rows, never read
    }
    float* enc_cands = p; p += (size_t)NCAND * D;
    float* cnorms = p; p += NCAND;
    float* enc_pers = p; p += (size_t)NPERS * D;
    float* pnorms = p; p += NPERS;
    if (((uintptr_t)p) & 7) p += 1;  // keep float2 loads on st aligned
    float* st = p;

    const int THR = 256;
    // ---- encodes ----
    if (stored) {
        encode_rows<<<(NMEM * 64 + THR - 1) / THR, THR, 0, stream>>>(
            semb, keys, NMEM, L, enc_keys, knorms);
        encode_rows<<<(NMEM * 64 + THR - 1) / THR, THR, 0, stream>>>(
            semb, values, NMEM, L, enc_vals, vnorms);
    }
    encode_rows<<<(NCAND * 64 + THR - 1) / THR, THR, 0, stream>>>(
        cemb, cands, NCAND, L, enc_cands, cnorms);
    encode_rows<<<1, THR, 0, stream>>>(semb, pers, NPERS, L, enc_pers, pnorms);
    // q: one "row" of LQ tokens -> st[0..127], ||q|| -> st[384]
    encode_rows<<<1, THR, 0, stream>>>(semb, xs, 1, LQ, st, st + 384);

    // ---- hop 1 (W = R_W) ----
    persona_hop<<<1, 128, 0, stream>>>(enc_pers, pnorms, RW, st, NPERS);
    if (stored)
        big_att2<<<1024, THR, 0, stream>>>(enc_keys, knorms, enc_vals, st, NMEM);
    else
        big_att_rc<<<1024, THR, 0, stream>>>(semb, keys, values, st, NMEM, L);
    finish_hop<<<1, 128, 0, stream>>>(RW, st);

    // ---- hop 2 (W = R2_W) ----
    persona_hop<<<1, 128, 0, stream>>>(enc_pers, pnorms, R2W, st, NPERS);
    if (stored)
        big_att2<<<1024, THR, 0, stream>>>(enc_keys, knorms, enc_vals, st, NMEM);
    else
        big_att_rc<<<1024, THR, 0, stream>>>(semb, keys, values, st, NMEM, L);
    finish_hop<<<1, 128, 0, stream>>>(R2W, st);

    // ---- final candidate cosine ----
    final_cands<<<(NCAND * 64 + THR - 1) / THR, THR, 0, stream>>>(
        enc_cands, cnorms, st, out, NCAND);

    (void)n_in; (void)out_size; (void)big_att;  // big_att superseded by big_att2
}

// Round 2
// 444.681 us; speedup vs baseline: 1.1875x; 1.1875x over previous
//
#include <hip/hip_runtime.h>
#include <math.h>
#include <stdint.h>

#define D 128
#define EPS 1e-6f

// ---------------------------------------------------------------------------
// state layout (floats), 16B-aligned base:
//   st[0..127]   : q
//   st[128..255] : q_plus
//   st[256..383] : hop accumulator (numerator of weighted value sum)
//   st[384]      : ||q||
//   st[385]      : ||q_plus||
//   st[386]      : sum of exp (softmax denominator accumulator)
// ---------------------------------------------------------------------------

__device__ __forceinline__ float wave_sum(float v) {
#pragma unroll
    for (int off = 32; off > 0; off >>= 1) v += __shfl_xor(v, off, 64);
    return v;
}

// ---------------------------------------------------------------------------
// Pair-encode: 2 rows per wave (half-wave each, float4 -> 1KB/load-instr).
// Compile-time L => full unroll => all L row-loads independent & in flight.
// ids preloaded once per row via lanes hl<L, broadcast with ds_bpermute.
// ---------------------------------------------------------------------------
template <int L>
__global__ void encode_pairs(const float* __restrict__ table,
                             const int* __restrict__ ids, int N,
                             float* __restrict__ rows_out,
                             float* __restrict__ norms_out) {
    const int lane = threadIdx.x & 63;
    const int half = lane >> 5;  // 0 or 1: which row of the pair
    const int hl = lane & 31;    // lane within half: channels 4*hl..4*hl+3
    int gw = (int)((blockIdx.x * blockDim.x + threadIdx.x) >> 6);
    int nw = (int)((gridDim.x * blockDim.x) >> 6);
    const int npair = (N + 1) >> 1;
    for (int p = gw; p < npair; p += nw) {
        const int row = 2 * p + half;
        const bool valid = row < N;
        const int rowc = valid ? row : (N - 1);
        int myid = 0;
        if (hl < L) myid = ids[(long)rowc * L + hl];
        float4 acc = {0.f, 0.f, 0.f, 0.f};
#pragma unroll
        for (int t = 0; t < L; ++t) {
            const int idx = __shfl(myid, (half << 5) + t, 64);
            const float4 e = *(const float4*)(table + (long)idx * D + 4 * hl);
            acc.x += e.x; acc.y += e.y; acc.z += e.z; acc.w += e.w;
        }
        if (valid) *(float4*)(rows_out + (long)row * D + 4 * hl) = acc;
        float sq = acc.x * acc.x + acc.y * acc.y + acc.z * acc.z + acc.w * acc.w;
#pragma unroll
        for (int off = 16; off > 0; off >>= 1) sq += __shfl_xor(sq, off, 32);
        if (valid && hl == 0) norms_out[row] = sqrtf(sq);
    }
}

// One wave per row, float2, runtime L (small-N / odd-L path: persona, q).
__global__ void encode_rows(const float* __restrict__ table,
                            const int* __restrict__ ids, int N, int L,
                            float* __restrict__ rows_out,
                            float* __restrict__ norms_out) {
    int lane = threadIdx.x & 63;
    int gw = (int)((blockIdx.x * blockDim.x + threadIdx.x) >> 6);
    int nw = (int)((gridDim.x * blockDim.x) >> 6);
    for (int i = gw; i < N; i += nw) {
        float2 acc = {0.f, 0.f};
        const int* row_ids = ids + (long)i * L;
        for (int t = 0; t < L; ++t) {
            int idx = row_ids[t];
            const float2 e = *(const float2*)(table + (long)idx * D + 2 * lane);
            acc.x += e.x;
            acc.y += e.y;
        }
        *(float2*)(rows_out + (long)i * D + 2 * lane) = acc;
        float sq = wave_sum(acc.x * acc.x + acc.y * acc.y);
        if (lane == 0) norms_out[i] = sqrtf(sq);
    }
}

// Single block, 128 threads. Persona attention (NP rows) + q_plus=(q+hop)@W.T
// + ||q_plus||; zeroes the big-attention accumulators for the following pass.
__global__ void persona_hop(const float* __restrict__ pers_rows,
                            const float* __restrict__ pers_norms,
                            const float* __restrict__ W,
                            float* __restrict__ st, int NP) {
    __shared__ float qsh[D];
    __shared__ float att[64];
    __shared__ float qh[D];
    __shared__ float red[2];
    int tid = threadIdx.x;  // 0..127
    qsh[tid] = st[tid];
    __syncthreads();
    if (tid < NP) {
        float dot = 0.f;
        for (int d2 = 0; d2 < D; ++d2) dot += pers_rows[tid * D + d2] * qsh[d2];
        att[tid] = dot / fmaxf(pers_norms[tid] * st[384], EPS);
    }
    __syncthreads();
    if (tid == 0) {
        float m = -1e30f;
        for (int p = 0; p < NP; ++p) m = fmaxf(m, att[p]);
        float s = 0.f;
        for (int p = 0; p < NP; ++p) { att[p] = __expf(att[p] - m); s += att[p]; }
        float inv = 1.f / s;
        for (int p = 0; p < NP; ++p) att[p] *= inv;
    }
    __syncthreads();
    float h = 0.f;
    for (int p = 0; p < NP; ++p) h += att[p] * pers_rows[p * D + tid];
    qh[tid] = qsh[tid] + h;
    __syncthreads();
    float qp = 0.f;
    for (int d2 = 0; d2 < D; ++d2) qp += W[tid * D + d2] * qh[d2];
    st[128 + tid] = qp;
    float sq = wave_sum(qp * qp);
    if ((tid & 63) == 0) red[tid >> 6] = sq;
    __syncthreads();
    if (tid == 0) st[385] = sqrtf(red[0] + red[1]);
    // zero big-attention accumulators
    st[256 + tid] = 0.f;
    if (tid == 0) st[386] = 0.f;
}

// Fused big attention over precomputed key/value rows: per row
// e_i = exp(cos(q_plus, k_i)); accumulate sum_i e_i * v_i and sum_i e_i.
// cos in [-1,1] so exp needs no max subtraction. 2 rows/wave, float4.
__global__ void big_att2(const float* __restrict__ krows,
                         const float* __restrict__ knorms,
                         const float* __restrict__ vrows,
                         float* __restrict__ st, int N) {
    __shared__ float s[129];
    int tid = threadIdx.x;
    int lane = tid & 63;
    int half = lane >> 5, hl = lane & 31;
    int gw = (int)((blockIdx.x * blockDim.x + tid) >> 6);
    int nw = (int)((gridDim.x * blockDim.x) >> 6);
    const float4 qp = *(const float4*)(st + 128 + 4 * hl);
    const float qpn = st[385];
    float4 acc = {0.f, 0.f, 0.f, 0.f};
    float esum = 0.f;
    const int npair = N >> 1;  // N even (65536)
    for (int p = gw; p < npair; p += nw) {
        const int i = 2 * p + half;
        const float4 k = *(const float4*)(krows + (long)i * D + 4 * hl);
        float dot = k.x * qp.x + k.y * qp.y + k.z * qp.z + k.w * qp.w;
#pragma unroll
        for (int off = 16; off > 0; off >>= 1) dot += __shfl_xor(dot, off, 32);
        const float c = dot / fmaxf(knorms[i] * qpn, EPS);
        const float e = __expf(c);
        const float4 v = *(const float4*)(vrows + (long)i * D + 4 * hl);
        acc.x += e * v.x; acc.y += e * v.y; acc.z += e * v.z; acc.w += e * v.w;
        if (hl == 0) esum += e;
    }
    // merge the two halves (same channels, different row subsets)
    acc.x += __shfl_xor(acc.x, 32, 64);
    acc.y += __shfl_xor(acc.y, 32, 64);
    acc.z += __shfl_xor(acc.z, 32, 64);
    acc.w += __shfl_xor(acc.w, 32, 64);
    esum += __shfl_xor(esum, 32, 64);
    if (tid < 129) s[tid] = 0.f;
    __syncthreads();
    if (half == 0) {
        atomicAdd(&s[4 * hl + 0], acc.x);
        atomicAdd(&s[4 * hl + 1], acc.y);
        atomicAdd(&s[4 * hl + 2], acc.z);
        atomicAdd(&s[4 * hl + 3], acc.w);
        if (hl == 0) atomicAdd(&s[128], esum);
    }
    __syncthreads();
    if (tid < 128) atomicAdd(&st[256 + tid], s[tid]);
    if (tid == 128) atomicAdd(&st[386], s[128]);
}

// Fallback: recompute key/value rows from the embedding table (used when
// d_ws is too small to hold the encoded rows).
__global__ void big_att_rc(const float* __restrict__ emb,
                           const int* __restrict__ kids,
                           const int* __restrict__ vids,
                           float* __restrict__ st, int N, int L) {
    __shared__ float s[129];
    int tid = threadIdx.x;
    int lane = tid & 63;
    int gw = (int)((blockIdx.x * blockDim.x + tid) >> 6);
    int nw = (int)((gridDim.x * blockDim.x) >> 6);
    float2 qp = *(const float2*)(st + 128 + 2 * lane);
    float qpn = st[385];
    float2 acc = {0.f, 0.f};
    float esum = 0.f;
    for (int i = gw; i < N; i += nw) {
        float2 k = {0.f, 0.f};
        const int* kr = kids + (long)i * L;
        for (int t = 0; t < L; ++t) {
            const float2 e = *(const float2*)(emb + (long)kr[t] * D + 2 * lane);
            k.x += e.x;
            k.y += e.y;
        }
        float nsq = wave_sum(k.x * k.x + k.y * k.y);
        float dot = wave_sum(k.x * qp.x + k.y * qp.y);
        float c = dot / fmaxf(sqrtf(nsq) * qpn, EPS);
        float e = __expf(c);
        float2 v = {0.f, 0.f};
        const int* vr = vids + (long)i * L;
        for (int t = 0; t < L; ++t) {
            const float2 ev = *(const float2*)(emb + (long)vr[t] * D + 2 * lane);
            v.x += ev.x;
            v.y += ev.y;
        }
        acc.x += e * v.x;
        acc.y += e * v.y;
        esum += e;
    }
    if (tid < 129) s[tid] = 0.f;
    __syncthreads();
    atomicAdd(&s[2 * lane], acc.x);
    atomicAdd(&s[2 * lane + 1], acc.y);
    if (lane == 0) atomicAdd(&s[128], esum);
    __syncthreads();
    if (tid < 128) atomicAdd(&st[256 + tid], s[tid]);
    if (tid == 128) atomicAdd(&st[386], s[128]);
}

// Single block, 128 threads: hop = acc/sum; q = (q_plus + hop) @ W.T; ||q||.
__global__ void finish_hop(const float* __restrict__ W, float* __restrict__ st) {
    __shared__ float qh[D];
    __shared__ float red[2];
    int tid = threadIdx.x;  // 0..127
    float inv = 1.f / st[386];
    qh[tid] = st[128 + tid] + st[256 + tid] * inv;
    __syncthreads();
    float qn = 0.f;
    for (int d2 = 0; d2 < D; ++d2) qn += W[tid * D + d2] * qh[d2];
    st[tid] = qn;
    float sq = wave_sum(qn * qn);
    if ((tid & 63) == 0) red[tid >> 6] = sq;
    __syncthreads();
    if (tid == 0) st[384] = sqrtf(red[0] + red[1]);
}

// One wave per candidate row: out[i] = cos(q, c_i).
__global__ void final_cands(const float* __restrict__ crows,
                            const float* __restrict__ cnorms,
                            const float* __restrict__ st,
                            float* __restrict__ out, int N) {
    int lane = threadIdx.x & 63;
    int gw = (int)((blockIdx.x * blockDim.x + threadIdx.x) >> 6);
    int nw = (int)((gridDim.x * blockDim.x) >> 6);
    float2 q = *(const float2*)(st + 2 * lane);
    float qn = st[384];
    for (int i = gw; i < N; i += nw) {
        const float2 c = *(const float2*)(crows + (long)i * D + 2 * lane);
        float dot = wave_sum(c.x * q.x + c.y * q.y);
        if (lane == 0) out[i] = dot / fmaxf(cnorms[i] * qn, EPS);
    }
}

extern "C" void kernel_launch(void* const* d_in, const int* in_sizes, int n_in,
                              void* d_out, int out_size, void* d_ws, size_t ws_size,
                              hipStream_t stream) {
    const int* xs = (const int*)d_in[0];
    const int* cands = (const int*)d_in[1];
    const int* pers = (const int*)d_in[2];
    const int* keys = (const int*)d_in[3];
    const int* values = (const int*)d_in[4];
    // d_in[5] = label, unused by the forward pass
    const float* semb = (const float*)d_in[6];
    const float* cemb = (const float*)d_in[7];
    const float* RW = (const float*)d_in[8];
    const float* R2W = (const float*)d_in[9];
    float* out = (float*)d_out;

    const int L = 20;
    const int LQ = in_sizes[0];
    const int NMEM = in_sizes[3] / L;   // 65536
    const int NCAND = in_sizes[1] / L;  // 10000
    const int NPERS = in_sizes[2] / L;  // 20

    size_t full_need =
        ((size_t)NMEM * D * 2 + (size_t)NMEM * 2 + (size_t)NCAND * D + NCAND +
         (size_t)NPERS * D + NPERS + 512) * sizeof(float);
    bool stored = (d_ws != nullptr) && (ws_size >= full_need);

    float* p = (float*)d_ws;
    float *enc_keys = nullptr, *enc_vals = nullptr, *knorms = nullptr, *vnorms = nullptr;
    if (stored) {
        enc_keys = p; p += (size_t)NMEM * D;
        enc_vals = p; p += (size_t)NMEM * D;
        knorms = p; p += NMEM;
        vnorms = p; p += NMEM;  // written, never read
    }
    float* enc_cands = p; p += (size_t)NCAND * D;
    float* cnorms = p; p += NCAND;
    float* enc_pers = p; p += (size_t)NPERS * D;
    float* pnorms = p; p += NPERS;
    while (((uintptr_t)p) & 15) p += 1;  // 16B-align st for float4 loads
    float* st = p;

    const int THR = 256;
    // ---- encodes ----
    if (stored) {
        int npair = (NMEM + 1) / 2;
        int blocks = (npair + 3) / 4;  // 4 waves/block
        encode_pairs<20><<<blocks, THR, 0, stream>>>(semb, keys, NMEM, enc_keys, knorms);
        encode_pairs<20><<<blocks, THR, 0, stream>>>(semb, values, NMEM, enc_vals, vnorms);
    }
    {
        int npair = (NCAND + 1) / 2;
        int blocks = (npair + 3) / 4;
        encode_pairs<20><<<blocks, THR, 0, stream>>>(cemb, cands, NCAND, enc_cands, cnorms);
    }
    encode_rows<<<1, THR, 0, stream>>>(semb, pers, NPERS, L, enc_pers, pnorms);
    // q: one "row" of LQ tokens -> st[0..127], ||q|| -> st[384]
    if (LQ == 32)
        encode_pairs<32><<<1, 64, 0, stream>>>(semb, xs, 1, st, st + 384);
    else
        encode_rows<<<1, 64, 0, stream>>>(semb, xs, 1, LQ, st, st + 384);

    // ---- hop 1 (W = R_W) ----
    persona_hop<<<1, 128, 0, stream>>>(enc_pers, pnorms, RW, st, NPERS);
    if (stored)
        big_att2<<<1024, THR, 0, stream>>>(enc_keys, knorms, enc_vals, st, NMEM);
    else
        big_att_rc<<<1024, THR, 0, stream>>>(semb, keys, values, st, NMEM, L);
    finish_hop<<<1, 128, 0, stream>>>(RW, st);

    // ---- hop 2 (W = R2_W) ----
    persona_hop<<<1, 128, 0, stream>>>(enc_pers, pnorms, R2W, st, NPERS);
    if (stored)
        big_att2<<<1024, THR, 0, stream>>>(enc_keys, knorms, enc_vals, st, NMEM);
    else
        big_att_rc<<<1024, THR, 0, stream>>>(semb, keys, values, st, NMEM, L);
    finish_hop<<<1, 128, 0, stream>>>(R2W, st);

    // ---- final candidate cosine ----
    final_cands<<<(NCAND * 64 + THR - 1) / THR, THR, 0, stream>>>(
        enc_cands, cnorms, st, out, NCAND);

    (void)n_in; (void)out_size;
}

// Round 3
// 361.195 us; speedup vs baseline: 1.4620x; 1.2311x over previous
//
#include <hip/hip_runtime.h>
#include <math.h>
#include <stdint.h>

#define D 128
#define EPS 1e-6f
typedef unsigned short u16;

// ---------------------------------------------------------------------------
// state layout (floats), 16B-aligned base:
//   st[0..127]   : q
//   st[128..255] : q_plus
//   st[256..383] : hop accumulator (numerator of weighted value sum)
//   st[384]      : ||q||
//   st[385]      : ||q_plus||
//   st[386]      : sum of exp (softmax denominator accumulator)
// ---------------------------------------------------------------------------

__device__ __forceinline__ float wave_sum(float v) {
#pragma unroll
    for (int off = 32; off > 0; off >>= 1) v += __shfl_xor(v, off, 64);
    return v;
}

__device__ __forceinline__ float bf2f(u16 h) {
    union { unsigned u; float f; } x;
    x.u = ((unsigned)h) << 16;
    return x.f;
}
__device__ __forceinline__ u16 f2bf(float f) {  // round-to-nearest-even
    union { float f; unsigned u; } x;
    x.f = f;
    unsigned u = x.u;
    return (u16)((u + 0x7fff + ((u >> 16) & 1)) >> 16);
}

// Streaming fp32 -> bf16 table conversion (RNE), float4/ushort4 vectorized.
__global__ void table_to_bf16(const float4* __restrict__ src,
                              ushort4* __restrict__ dst, int n4) {
    int i = blockIdx.x * blockDim.x + threadIdx.x;
    if (i < n4) {
        float4 v = src[i];
        ushort4 o;
        o.x = f2bf(v.x); o.y = f2bf(v.y); o.z = f2bf(v.z); o.w = f2bf(v.w);
        dst[i] = o;
    }
}

// ---------------------------------------------------------------------------
// Fused key+value encode from the bf16 table. 2 rows per wave (half-wave
// each, ushort4 = 4 channels/lane); per pair 40 independent row-gathers in
// flight. Accumulate fp32, store rows bf16 (RNE). knorms from fp32 sums.
// ---------------------------------------------------------------------------
template <int L>
__global__ void encode_kv_bf16(const u16* __restrict__ tbl,
                               const int* __restrict__ kids,
                               const int* __restrict__ vids, int N,
                               u16* __restrict__ krows, u16* __restrict__ vrows,
                               float* __restrict__ knorms) {
    const int lane = threadIdx.x & 63;
    const int half = lane >> 5;
    const int hl = lane & 31;
    int gw = (int)((blockIdx.x * blockDim.x + threadIdx.x) >> 6);
    int nw = (int)((gridDim.x * blockDim.x) >> 6);
    const int npair = (N + 1) >> 1;
    for (int p = gw; p < npair; p += nw) {
        const int row = 2 * p + half;
        const bool valid = row < N;
        const int rowc = valid ? row : (N - 1);
        int kid = 0, vid = 0;
        if (hl < L) {
            kid = kids[(long)rowc * L + hl];
            vid = vids[(long)rowc * L + hl];
        }
        float4 ka = {0.f, 0.f, 0.f, 0.f}, va = {0.f, 0.f, 0.f, 0.f};
#pragma unroll
        for (int t = 0; t < L; ++t) {
            const int ki = __shfl(kid, (half << 5) + t, 64);
            const int vi = __shfl(vid, (half << 5) + t, 64);
            const ushort4 ke = *(const ushort4*)(tbl + (long)ki * D + 4 * hl);
            const ushort4 ve = *(const ushort4*)(tbl + (long)vi * D + 4 * hl);
            ka.x += bf2f(ke.x); ka.y += bf2f(ke.y);
            ka.z += bf2f(ke.z); ka.w += bf2f(ke.w);
            va.x += bf2f(ve.x); va.y += bf2f(ve.y);
            va.z += bf2f(ve.z); va.w += bf2f(ve.w);
        }
        if (valid) {
            ushort4 ko, vo;
            ko.x = f2bf(ka.x); ko.y = f2bf(ka.y); ko.z = f2bf(ka.z); ko.w = f2bf(ka.w);
            vo.x = f2bf(va.x); vo.y = f2bf(va.y); vo.z = f2bf(va.z); vo.w = f2bf(va.w);
            *(ushort4*)(krows + (long)row * D + 4 * hl) = ko;
            *(ushort4*)(vrows + (long)row * D + 4 * hl) = vo;
        }
        float sq = ka.x * ka.x + ka.y * ka.y + ka.z * ka.z + ka.w * ka.w;
#pragma unroll
        for (int off = 16; off > 0; off >>= 1) sq += __shfl_xor(sq, off, 32);
        if (valid && hl == 0) knorms[row] = sqrtf(sq);
    }
}

// fp32 pair-encode (candidates path stays full precision).
template <int L>
__global__ void encode_pairs(const float* __restrict__ table,
                             const int* __restrict__ ids, int N,
                             float* __restrict__ rows_out,
                             float* __restrict__ norms_out) {
    const int lane = threadIdx.x & 63;
    const int half = lane >> 5;
    const int hl = lane & 31;
    int gw = (int)((blockIdx.x * blockDim.x + threadIdx.x) >> 6);
    int nw = (int)((gridDim.x * blockDim.x) >> 6);
    const int npair = (N + 1) >> 1;
    for (int p = gw; p < npair; p += nw) {
        const int row = 2 * p + half;
        const bool valid = row < N;
        const int rowc = valid ? row : (N - 1);
        int myid = 0;
        if (hl < L) myid = ids[(long)rowc * L + hl];
        float4 acc = {0.f, 0.f, 0.f, 0.f};
#pragma unroll
        for (int t = 0; t < L; ++t) {
            const int idx = __shfl(myid, (half << 5) + t, 64);
            const float4 e = *(const float4*)(table + (long)idx * D + 4 * hl);
            acc.x += e.x; acc.y += e.y; acc.z += e.z; acc.w += e.w;
        }
        if (valid) *(float4*)(rows_out + (long)row * D + 4 * hl) = acc;
        float sq = acc.x * acc.x + acc.y * acc.y + acc.z * acc.z + acc.w * acc.w;
#pragma unroll
        for (int off = 16; off > 0; off >>= 1) sq += __shfl_xor(sq, off, 32);
        if (valid && hl == 0) norms_out[row] = sqrtf(sq);
    }
}

// Persona rows + q in one tiny dispatch. 1 block, 256 thr (4 waves);
// wave handles persona rows i, i+4, ... ; the i==NP slot is q (L=LQ).
__global__ void encode_small(const float* __restrict__ emb,
                             const int* __restrict__ pers, int NP, int LP,
                             const int* __restrict__ xs, int LQ,
                             float* __restrict__ pers_rows,
                             float* __restrict__ pnorms,
                             float* __restrict__ st) {
    int lane = threadIdx.x & 63;
    int w = threadIdx.x >> 6;
    for (int i = w; i <= NP; i += 4) {
        const int* ids;
        int L;
        float* out;
        float* nrm;
        if (i < NP) { ids = pers + (long)i * LP; L = LP; out = pers_rows + (long)i * D; nrm = pnorms + i; }
        else        { ids = xs; L = LQ; out = st; nrm = st + 384; }
        float2 acc = {0.f, 0.f};
        for (int t = 0; t < L; ++t) {
            int idx = ids[t];
            const float2 e = *(const float2*)(emb + (long)idx * D + 2 * lane);
            acc.x += e.x;
            acc.y += e.y;
        }
        *(float2*)(out + 2 * lane) = acc;
        float sq = wave_sum(acc.x * acc.x + acc.y * acc.y);
        if (lane == 0) *nrm = sqrtf(sq);
    }
}

// Single block, 128 threads. Persona attention + q_plus=(q+hop)@W.T + ||q_plus||;
// zeroes the big-attention accumulators.
__global__ void persona_hop(const float* __restrict__ pers_rows,
                            const float* __restrict__ pers_norms,
                            const float* __restrict__ W,
                            float* __restrict__ st, int NP) {
    __shared__ float qsh[D];
    __shared__ float att[64];
    __shared__ float qh[D];
    __shared__ float red[2];
    int tid = threadIdx.x;
    qsh[tid] = st[tid];
    __syncthreads();
    if (tid < NP) {
        float dot = 0.f;
        for (int d2 = 0; d2 < D; ++d2) dot += pers_rows[tid * D + d2] * qsh[d2];
        att[tid] = dot / fmaxf(pers_norms[tid] * st[384], EPS);
    }
    __syncthreads();
    if (tid == 0) {
        float m = -1e30f;
        for (int p = 0; p < NP; ++p) m = fmaxf(m, att[p]);
        float s = 0.f;
        for (int p = 0; p < NP; ++p) { att[p] = __expf(att[p] - m); s += att[p]; }
        float inv = 1.f / s;
        for (int p = 0; p < NP; ++p) att[p] *= inv;
    }
    __syncthreads();
    float h = 0.f;
    for (int p = 0; p < NP; ++p) h += att[p] * pers_rows[p * D + tid];
    qh[tid] = qsh[tid] + h;
    __syncthreads();
    float qp = 0.f;
    for (int d2 = 0; d2 < D; ++d2) qp += W[tid * D + d2] * qh[d2];
    st[128 + tid] = qp;
    float sq = wave_sum(qp * qp);
    if ((tid & 63) == 0) red[tid >> 6] = sq;
    __syncthreads();
    if (tid == 0) st[385] = sqrtf(red[0] + red[1]);
    st[256 + tid] = 0.f;
    if (tid == 0) st[386] = 0.f;
}

// Fused big attention over bf16 key/value rows. 2 rows/wave, ushort4 loads.
__global__ void big_att_bf16(const u16* __restrict__ krows,
                             const float* __restrict__ knorms,
                             const u16* __restrict__ vrows,
                             float* __restrict__ st, int N) {
    __shared__ float s[129];
    int tid = threadIdx.x;
    int lane = tid & 63;
    int half = lane >> 5, hl = lane & 31;
    int gw = (int)((blockIdx.x * blockDim.x + tid) >> 6);
    int nw = (int)((gridDim.x * blockDim.x) >> 6);
    const float4 qp = *(const float4*)(st + 128 + 4 * hl);
    const float qpn = st[385];
    float4 acc = {0.f, 0.f, 0.f, 0.f};
    float esum = 0.f;
    const int npair = N >> 1;
    for (int p = gw; p < npair; p += nw) {
        const int i = 2 * p + half;
        const ushort4 kh = *(const ushort4*)(krows + (long)i * D + 4 * hl);
        float dot = bf2f(kh.x) * qp.x + bf2f(kh.y) * qp.y +
                    bf2f(kh.z) * qp.z + bf2f(kh.w) * qp.w;
#pragma unroll
        for (int off = 16; off > 0; off >>= 1) dot += __shfl_xor(dot, off, 32);
        const float c = dot / fmaxf(knorms[i] * qpn, EPS);
        const float e = __expf(c);
        const ushort4 vh = *(const ushort4*)(vrows + (long)i * D + 4 * hl);
        acc.x += e * bf2f(vh.x);
        acc.y += e * bf2f(vh.y);
        acc.z += e * bf2f(vh.z);
        acc.w += e * bf2f(vh.w);
        if (hl == 0) esum += e;
    }
    acc.x += __shfl_xor(acc.x, 32, 64);
    acc.y += __shfl_xor(acc.y, 32, 64);
    acc.z += __shfl_xor(acc.z, 32, 64);
    acc.w += __shfl_xor(acc.w, 32, 64);
    esum += __shfl_xor(esum, 32, 64);
    if (tid < 129) s[tid] = 0.f;
    __syncthreads();
    if (half == 0) {
        atomicAdd(&s[4 * hl + 0], acc.x);
        atomicAdd(&s[4 * hl + 1], acc.y);
        atomicAdd(&s[4 * hl + 2], acc.z);
        atomicAdd(&s[4 * hl + 3], acc.w);
        if (hl == 0) atomicAdd(&s[128], esum);
    }
    __syncthreads();
    if (tid < 128) atomicAdd(&st[256 + tid], s[tid]);
    if (tid == 128) atomicAdd(&st[386], s[128]);
}

// Fallback: recompute key/value rows from the fp32 table (ws too small).
__global__ void big_att_rc(const float* __restrict__ emb,
                           const int* __restrict__ kids,
                           const int* __restrict__ vids,
                           float* __restrict__ st, int N, int L) {
    __shared__ float s[129];
    int tid = threadIdx.x;
    int lane = tid & 63;
    int gw = (int)((blockIdx.x * blockDim.x + tid) >> 6);
    int nw = (int)((gridDim.x * blockDim.x) >> 6);
    float2 qp = *(const float2*)(st + 128 + 2 * lane);
    float qpn = st[385];
    float2 acc = {0.f, 0.f};
    float esum = 0.f;
    for (int i = gw; i < N; i += nw) {
        float2 k = {0.f, 0.f};
        const int* kr = kids + (long)i * L;
        for (int t = 0; t < L; ++t) {
            const float2 e = *(const float2*)(emb + (long)kr[t] * D + 2 * lane);
            k.x += e.x;
            k.y += e.y;
        }
        float nsq = wave_sum(k.x * k.x + k.y * k.y);
        float dot = wave_sum(k.x * qp.x + k.y * qp.y);
        float c = dot / fmaxf(sqrtf(nsq) * qpn, EPS);
        float e = __expf(c);
        float2 v = {0.f, 0.f};
        const int* vr = vids + (long)i * L;
        for (int t = 0; t < L; ++t) {
            const float2 ev = *(const float2*)(emb + (long)vr[t] * D + 2 * lane);
            v.x += ev.x;
            v.y += ev.y;
        }
        acc.x += e * v.x;
        acc.y += e * v.y;
        esum += e;
    }
    if (tid < 129) s[tid] = 0.f;
    __syncthreads();
    atomicAdd(&s[2 * lane], acc.x);
    atomicAdd(&s[2 * lane + 1], acc.y);
    if (lane == 0) atomicAdd(&s[128], esum);
    __syncthreads();
    if (tid < 128) atomicAdd(&st[256 + tid], s[tid]);
    if (tid == 128) atomicAdd(&st[386], s[128]);
}

// finish hop with W1 (q = (q_plus+hop)@W1.T), then persona attention and
// q_plus for the next hop with W2. Single block, 128 threads.
__global__ void mid_hop(const float* __restrict__ W1, const float* __restrict__ W2,
                        const float* __restrict__ pers_rows,
                        const float* __restrict__ pers_norms,
                        float* __restrict__ st, int NP) {
    __shared__ float qh[D];
    __shared__ float qsh[D];
    __shared__ float att[64];
    __shared__ float red[2];
    int tid = threadIdx.x;
    float inv = 1.f / st[386];
    qh[tid] = st[128 + tid] + st[256 + tid] * inv;
    __syncthreads();
    float qn = 0.f;
    for (int d2 = 0; d2 < D; ++d2) qn += W1[tid * D + d2] * qh[d2];
    qsh[tid] = qn;
    st[tid] = qn;
    float sq = wave_sum(qn * qn);
    if ((tid & 63) == 0) red[tid >> 6] = sq;
    __syncthreads();
    float qnorm = sqrtf(red[0] + red[1]);
    if (tid == 0) st[384] = qnorm;
    if (tid < NP) {
        float dot = 0.f;
        for (int d2 = 0; d2 < D; ++d2) dot += pers_rows[tid * D + d2] * qsh[d2];
        att[tid] = dot / fmaxf(pers_norms[tid] * qnorm, EPS);
    }
    __syncthreads();
    if (tid == 0) {
        float m = -1e30f;
        for (int p = 0; p < NP; ++p) m = fmaxf(m, att[p]);
        float s = 0.f;
        for (int p = 0; p < NP; ++p) { att[p] = __expf(att[p] - m); s += att[p]; }
        float is = 1.f / s;
        for (int p = 0; p < NP; ++p) att[p] *= is;
    }
    __syncthreads();
    float h = 0.f;
    for (int p = 0; p < NP; ++p) h += att[p] * pers_rows[p * D + tid];
    qh[tid] = qsh[tid] + h;
    __syncthreads();
    float qp = 0.f;
    for (int d2 = 0; d2 < D; ++d2) qp += W2[tid * D + d2] * qh[d2];
    st[128 + tid] = qp;
    float sq2 = wave_sum(qp * qp);
    if ((tid & 63) == 0) red[tid >> 6] = sq2;
    __syncthreads();
    if (tid == 0) st[385] = sqrtf(red[0] + red[1]);
    st[256 + tid] = 0.f;
    if (tid == 0) st[386] = 0.f;
}

// Single block, 128 threads: hop = acc/sum; q = (q_plus + hop) @ W.T; ||q||.
__global__ void finish_hop(const float* __restrict__ W, float* __restrict__ st) {
    __shared__ float qh[D];
    __shared__ float red[2];
    int tid = threadIdx.x;
    float inv = 1.f / st[386];
    qh[tid] = st[128 + tid] + st[256 + tid] * inv;
    __syncthreads();
    float qn = 0.f;
    for (int d2 = 0; d2 < D; ++d2) qn += W[tid * D + d2] * qh[d2];
    st[tid] = qn;
    float sq = wave_sum(qn * qn);
    if ((tid & 63) == 0) red[tid >> 6] = sq;
    __syncthreads();
    if (tid == 0) st[384] = sqrtf(red[0] + red[1]);
}

// One wave per candidate row: out[i] = cos(q, c_i). fp32 rows.
__global__ void final_cands(const float* __restrict__ crows,
                            const float* __restrict__ cnorms,
                            const float* __restrict__ st,
                            float* __restrict__ out, int N) {
    int lane = threadIdx.x & 63;
    int gw = (int)((blockIdx.x * blockDim.x + threadIdx.x) >> 6);
    int nw = (int)((gridDim.x * blockDim.x) >> 6);
    float2 q = *(const float2*)(st + 2 * lane);
    float qn = st[384];
    for (int i = gw; i < N; i += nw) {
        const float2 c = *(const float2*)(crows + (long)i * D + 2 * lane);
        float dot = wave_sum(c.x * q.x + c.y * q.y);
        if (lane == 0) out[i] = dot / fmaxf(cnorms[i] * qn, EPS);
    }
}

static inline size_t align16(size_t b) { return (b + 15) & ~(size_t)15; }

extern "C" void kernel_launch(void* const* d_in, const int* in_sizes, int n_in,
                              void* d_out, int out_size, void* d_ws, size_t ws_size,
                              hipStream_t stream) {
    const int* xs = (const int*)d_in[0];
    const int* cands = (const int*)d_in[1];
    const int* pers = (const int*)d_in[2];
    const int* keys = (const int*)d_in[3];
    const int* values = (const int*)d_in[4];
    const float* semb = (const float*)d_in[6];
    const float* cemb = (const float*)d_in[7];
    const float* RW = (const float*)d_in[8];
    const float* R2W = (const float*)d_in[9];
    float* out = (float*)d_out;

    const int L = 20;
    const int LQ = in_sizes[0];
    const int VD = in_sizes[6];         // V*D
    const int NMEM = in_sizes[3] / L;   // 65536
    const int NCAND = in_sizes[1] / L;  // 10000
    const int NPERS = in_sizes[2] / L;  // 20

    // ---- workspace layout ----
    size_t need = align16((size_t)VD * 2) + 2 * align16((size_t)NMEM * D * 2) +
                  align16((size_t)NMEM * 4) + align16((size_t)NCAND * D * 4) +
                  align16((size_t)NCAND * 4) + align16((size_t)NPERS * D * 4) +
                  align16((size_t)NPERS * 4) + 512 * 4;
    bool stored = (d_ws != nullptr) && (ws_size >= need);

    char* base = (char*)d_ws;
    u16 *tbl16 = nullptr, *kb = nullptr, *vb = nullptr;
    float* knorms = nullptr;
    if (stored) {
        tbl16 = (u16*)base; base += align16((size_t)VD * 2);
        kb = (u16*)base;    base += align16((size_t)NMEM * D * 2);
        vb = (u16*)base;    base += align16((size_t)NMEM * D * 2);
        knorms = (float*)base; base += align16((size_t)NMEM * 4);
    }
    float* enc_cands = (float*)base; base += align16((size_t)NCAND * D * 4);
    float* cnorms = (float*)base;    base += align16((size_t)NCAND * 4);
    float* enc_pers = (float*)base;  base += align16((size_t)NPERS * D * 4);
    float* pnorms = (float*)base;    base += align16((size_t)NPERS * 4);
    float* st = (float*)base;

    const int THR = 256;
    // ---- encodes ----
    if (stored) {
        int n4 = VD / 4;
        table_to_bf16<<<(n4 + THR - 1) / THR, THR, 0, stream>>>(
            (const float4*)semb, (ushort4*)tbl16, n4);
        int npair = (NMEM + 1) / 2;
        encode_kv_bf16<20><<<(npair + 3) / 4, THR, 0, stream>>>(
            tbl16, keys, values, NMEM, kb, vb, knorms);
    }
    {
        int npair = (NCAND + 1) / 2;
        encode_pairs<20><<<(npair + 3) / 4, THR, 0, stream>>>(
            cemb, cands, NCAND, enc_cands, cnorms);
    }
    encode_small<<<1, THR, 0, stream>>>(semb, pers, NPERS, L, xs, LQ,
                                        enc_pers, pnorms, st);

    // ---- hop 1 (W = R_W) ----
    persona_hop<<<1, 128, 0, stream>>>(enc_pers, pnorms, RW, st, NPERS);
    if (stored)
        big_att_bf16<<<1024, THR, 0, stream>>>(kb, knorms, vb, st, NMEM);
    else
        big_att_rc<<<1024, THR, 0, stream>>>(semb, keys, values, st, NMEM, L);

    // ---- finish hop 1 + persona for hop 2 (W = R2_W) ----
    mid_hop<<<1, 128, 0, stream>>>(RW, R2W, enc_pers, pnorms, st, NPERS);
    if (stored)
        big_att_bf16<<<1024, THR, 0, stream>>>(kb, knorms, vb, st, NMEM);
    else
        big_att_rc<<<1024, THR, 0, stream>>>(semb, keys, values, st, NMEM, L);
    finish_hop<<<1, 128, 0, stream>>>(R2W, st);

    // ---- final candidate cosine ----
    final_cands<<<(NCAND * 64 + THR - 1) / THR, THR, 0, stream>>>(
        enc_cands, cnorms, st, out, NCAND);

    (void)n_in; (void)out_size;
}